// Round 13
// baseline (444.354 us; speedup 1.0000x reference)
//
#include <hip/hip_runtime.h>
#include <cstdio>
#include <cstdint>

typedef _Float16 f16x8 __attribute__((ext_vector_type(8)));
typedef float f32x4 __attribute__((ext_vector_type(4)));

__device__ inline unsigned short f2bf(float f) {  // fp32 -> bf16 RNE
  unsigned u = __float_as_uint(f);
  u += 0x7fffu + ((u >> 16) & 1u);
  return (unsigned short)(u >> 16);
}
__device__ inline float bf2f(unsigned short h) {
  return __uint_as_float(((unsigned)h) << 16);
}
__device__ inline unsigned short f2h(float f) {   // fp32 -> fp16 RNE (bits)
  union { _Float16 h; unsigned short u; } cv;
  cv.h = (_Float16)f;
  return cv.u;
}

// ================= fused prep: zero psum/gcnt, feat->bf16, W->fp16^T ======

__global__ __launch_bounds__(256)
void k_prep(double* __restrict__ psum, float* __restrict__ gcnt,
            const float* __restrict__ feature, ushort* __restrict__ featb,
            const float* __restrict__ W1, ushort* __restrict__ w1h,
            const float* __restrict__ W2, ushort* __restrict__ w2h,
            const float* __restrict__ W3, ushort* __restrict__ w3h,
            int BC, int Bn, int NF, int F, int D2, int D3,
            int nB, int nC) {
  int b = blockIdx.x;
  int t = threadIdx.x;
  if (b < nB) {
    int i = b * 256 + t;
    if (i < BC) psum[i] = 0.0;
    if (i < Bn) gcnt[i] = 0.f;
  } else if (b < nB + nC) {
    int base = ((b - nB) * 256 + t) * 4;
    if (base < NF) {
      float4 v = *reinterpret_cast<const float4*>(feature + base);
      ushort4 h;
      h.x = f2bf(v.x); h.y = f2bf(v.y); h.z = f2bf(v.z); h.w = f2bf(v.w);
      *reinterpret_cast<ushort4*>(featb + base) = h;
    }
  } else {
    int idx = (b - nB - nC) * 256 + t;
    int s1 = F * F, s2 = s1 + F * D2, s3 = s2 + D2 * D3;
    if (idx < s1) {
      int k = idx / F, n = idx - k * F;
      w1h[(size_t)n * F + k] = f2h(W1[idx]);
    } else if (idx < s2) {
      int i2 = idx - s1; int k = i2 / D2, n = i2 - k * D2;
      w2h[(size_t)n * F + k] = f2h(W2[i2]);
    } else if (idx < s3) {
      int i3 = idx - s2; int k = i3 / D3, n = i3 - k * D3;
      w3h[(size_t)n * D2 + k] = f2h(W3[i3]);
    }
  }
}

// ================= sort-based CSR build (ZERO global atomics) =============

#define EPB 4096

__global__ __launch_bounds__(256)
void k_bhist(const int* __restrict__ dst, int* __restrict__ H,
             int NB, int E) {
  __shared__ int hist[512];
  const int t = threadIdx.x;
  for (int i = t; i < NB; i += 256) hist[i] = 0;
  __syncthreads();
  const int base = blockIdx.x * EPB + t;
#pragma unroll
  for (int j = 0; j < EPB / 256; j++) {
    int e = base + 256 * j;
    if (e < E) atomicAdd(&hist[dst[e] >> 8], 1);
  }
  __syncthreads();
  for (int i = t; i < NB; i += 256) H[(size_t)blockIdx.x * NB + i] = hist[i];
}

__global__ __launch_bounds__(256)
void k_bscan1(const int* __restrict__ H, int* __restrict__ S,
              int* __restrict__ bsum, int NB, int NBLK, int T) {
  __shared__ int sh[256];
  const int t = threadIdx.x;
  const int base = blockIdx.x * 1024;
  int v[4]; int s = 0;
#pragma unroll
  for (int j = 0; j < 4; j++) {
    int idx = base + t * 4 + j;
    if (idx < T) {
      int bin = idx / NBLK, bi = idx - bin * NBLK;
      v[j] = H[(size_t)bi * NB + bin];
    } else v[j] = 0;
    s += v[j];
  }
  sh[t] = s;
  __syncthreads();
  for (int off = 1; off < 256; off <<= 1) {
    int x = (t >= off) ? sh[t - off] : 0;
    __syncthreads();
    sh[t] += x;
    __syncthreads();
  }
  int run = sh[t] - s;
#pragma unroll
  for (int j = 0; j < 4; j++) {
    int idx = base + t * 4 + j;
    if (idx < T) S[idx] = run;
    run += v[j];
  }
  if (t == 255) bsum[blockIdx.x] = sh[255];
}

__global__ __launch_bounds__(256)
void k_bscan23(int* __restrict__ S, const int* __restrict__ bsum, int T) {
  __shared__ int spre;
  const int chunk = blockIdx.x >> 2;
  if (threadIdx.x == 0) {
    int pre = 0;
    for (int t = 0; t < chunk; t++) pre += bsum[t];
    spre = pre;
  }
  __syncthreads();
  int i = blockIdx.x * 256 + threadIdx.x;
  if (i < T) S[i] += spre;
}

__global__ __launch_bounds__(256)
void k_bscatter(const int* __restrict__ src, const int* __restrict__ dst,
                const float* __restrict__ ew, const int* __restrict__ S,
                int* __restrict__ sdst, int2* __restrict__ ssw,
                int NB, int NBLK, int E) {
  __shared__ int cnt[512];
  __shared__ int sbase[512];
  const int t = threadIdx.x, bi = blockIdx.x;
  for (int i = t; i < NB; i += 256) {
    cnt[i] = 0;
    sbase[i] = S[(size_t)i * NBLK + bi];
  }
  __syncthreads();
  const int base = bi * EPB + t;
#pragma unroll
  for (int j = 0; j < EPB / 256; j++) {
    int e = base + 256 * j;
    if (e < E) {
      int d = dst[e];
      int bin = d >> 8;
      int r = atomicAdd(&cnt[bin], 1);
      int pos = sbase[bin] + r;
      sdst[pos] = d;
      ssw[pos] = make_int2(src[e], __float_as_int(ew[e]));
    }
  }
}

__global__ __launch_bounds__(256)
void k_bprocA(const int* __restrict__ sdst, const int2* __restrict__ ssw,
              const int* __restrict__ S, int* __restrict__ cntN,
              float* __restrict__ wsumN, int NB, int NBLK, int N, int E) {
  __shared__ int cnt[256];
  __shared__ float wsm[256];
  const int t = threadIdx.x, bin = blockIdx.x;
  cnt[t] = 0; wsm[t] = 0.f;
  __syncthreads();
  const int start = S[(size_t)bin * NBLK];
  const int end = (bin + 1 < NB) ? S[(size_t)(bin + 1) * NBLK] : E;
  for (int p = start + t; p < end; p += 256) {
    int ld = sdst[p] & 255;
    atomicAdd(&cnt[ld], 1);
    atomicAdd(&wsm[ld], __int_as_float(ssw[p].y));
  }
  __syncthreads();
  int n = bin * 256 + t;
  if (n < N) { cntN[n] = cnt[t]; wsumN[n] = wsm[t]; }
}

__global__ __launch_bounds__(256)
void k_scan1(const int* __restrict__ cntN, const float* __restrict__ wsumN,
             int* __restrict__ rs, int* __restrict__ bsum,
             float* __restrict__ dinv, float* __restrict__ sn, int N) {
  __shared__ int sh[256];
  const int t = threadIdx.x;
  const int base = blockIdx.x * 1024;
  int v[4]; int s = 0;
#pragma unroll
  for (int j = 0; j < 4; j++) {
    int idx = base + t * 4 + j;
    if (idx < N) {
      v[j] = cntN[idx];
      double deg = 1.0 + (double)wsumN[idx];
      float r = (float)(1.0 / sqrt(deg));
      dinv[idx] = r;
      sn[idx] = r * r;
    } else v[j] = 0;
    s += v[j];
  }
  sh[t] = s;
  __syncthreads();
  for (int off = 1; off < 256; off <<= 1) {
    int x = (t >= off) ? sh[t - off] : 0;
    __syncthreads();
    sh[t] += x;
    __syncthreads();
  }
  int run = sh[t] - s;
#pragma unroll
  for (int j = 0; j < 4; j++) {
    int idx = base + t * 4 + j;
    if (idx < N) rs[idx] = run;
    run += v[j];
  }
  if (t == 255) bsum[blockIdx.x] = sh[255];
}

__global__ __launch_bounds__(256)
void k_scan23(int* __restrict__ rs, const int* __restrict__ bsum, int N, int E) {
  __shared__ int spre;
  const int chunk = blockIdx.x >> 2;
  if (threadIdx.x == 0) {
    int pre = 0;
    for (int t = 0; t < chunk; t++) pre += bsum[t];
    spre = pre;
  }
  __syncthreads();
  int i = blockIdx.x * 256 + threadIdx.x;
  if (i < N) rs[i] += spre;
  if (i == 0) rs[N] = E;   // row-end sentinel
}

__global__ __launch_bounds__(256)
void k_bprocB(const int* __restrict__ sdst, const int2* __restrict__ ssw,
              const int* __restrict__ S, const int* __restrict__ rs,
              const float* __restrict__ dinv,
              int2* __restrict__ epack, int NB, int NBLK, int N, int E) {
  __shared__ int cnt[256];
  __shared__ float sdv[256];
  __shared__ int srs[256];
  const int t = threadIdx.x, bin = blockIdx.x;
  cnt[t] = 0;
  int n = bin * 256 + t;
  sdv[t] = (n < N) ? dinv[n] : 0.f;
  srs[t] = (n < N) ? rs[n] : 0;
  __syncthreads();
  const int start = S[(size_t)bin * NBLK];
  const int end = (bin + 1 < NB) ? S[(size_t)(bin + 1) * NBLK] : E;
  for (int p = start + t; p < end; p += 256) {
    int d = sdst[p];
    int ld = d & 255;
    int2 sw = ssw[p];
    int r = atomicAdd(&cnt[ld], 1);
    float w = dinv[sw.x] * __int_as_float(sw.y) * sdv[ld];
    epack[srs[ld] + r] = make_int2(sw.x, __float_as_int(w));
  }
}

// ================= CSR gather aggregation (bf16 in, fp16 out) ======
// lanes/row = D/16; each lane covers 16 cols via two int4 loads per gather
// (4 outstanding loads with the x2 edge unroll). Per-column accumulation
// order identical to R12 -> bit-identical output.

__device__ inline void bf8_fma(const int4 v, float w, float* acc) {
  acc[0] = fmaf(__uint_as_float((unsigned)v.x << 16), w, acc[0]);
  acc[1] = fmaf(__uint_as_float((unsigned)v.x & 0xffff0000u), w, acc[1]);
  acc[2] = fmaf(__uint_as_float((unsigned)v.y << 16), w, acc[2]);
  acc[3] = fmaf(__uint_as_float((unsigned)v.y & 0xffff0000u), w, acc[3]);
  acc[4] = fmaf(__uint_as_float((unsigned)v.z << 16), w, acc[4]);
  acc[5] = fmaf(__uint_as_float((unsigned)v.z & 0xffff0000u), w, acc[5]);
  acc[6] = fmaf(__uint_as_float((unsigned)v.w << 16), w, acc[6]);
  acc[7] = fmaf(__uint_as_float((unsigned)v.w & 0xffff0000u), w, acc[7]);
}
__device__ inline void bf8_scale(const int4 v, float s, float* acc) {
  acc[0] = s * __uint_as_float((unsigned)v.x << 16);
  acc[1] = s * __uint_as_float((unsigned)v.x & 0xffff0000u);
  acc[2] = s * __uint_as_float((unsigned)v.y << 16);
  acc[3] = s * __uint_as_float((unsigned)v.y & 0xffff0000u);
  acc[4] = s * __uint_as_float((unsigned)v.z << 16);
  acc[5] = s * __uint_as_float((unsigned)v.z & 0xffff0000u);
  acc[6] = s * __uint_as_float((unsigned)v.w << 16);
  acc[7] = s * __uint_as_float((unsigned)v.w & 0xffff0000u);
}

template<int LOG2L>
__global__ __launch_bounds__(256)
void k_aggregate_b(const ushort* __restrict__ Xb, const int* __restrict__ rs,
                   const int2* __restrict__ epack, const float* __restrict__ sn,
                   ushort* __restrict__ AH, int N) {
  const int t = blockIdx.x * blockDim.x + threadIdx.x;
  const int row = t >> LOG2L;
  if (row >= N) return;
  const int L = 1 << LOG2L;
  const int D = L << 4;                  // 16 cols per lane
  const int c = (t & (L - 1)) << 4;

  float acc[16];
  {
    const ushort* rp = Xb + (size_t)row * D + c;
    int4 v0 = *reinterpret_cast<const int4*>(rp);
    int4 v1 = *reinterpret_cast<const int4*>(rp + 8);
    float s = sn[row];
    bf8_scale(v0, s, acc);
    bf8_scale(v1, s, acc + 8);
  }
  const int p0 = rs[row], pe = rs[row + 1];
  int i = p0;
  if ((i & 1) && i < pe) {   // peel to 16B-aligned pair index
    int2 e = epack[i];
    const ushort* rp = Xb + (size_t)e.x * D + c;
    int4 v0 = *reinterpret_cast<const int4*>(rp);
    int4 v1 = *reinterpret_cast<const int4*>(rp + 8);
    float w = __int_as_float(e.y);
    bf8_fma(v0, w, acc);
    bf8_fma(v1, w, acc + 8);
    i++;
  }
  for (; i + 2 <= pe; i += 2) {
    int4 e2 = *reinterpret_cast<const int4*>(&epack[i]);
    const ushort* ra = Xb + (size_t)e2.x * D + c;
    const ushort* rb = Xb + (size_t)e2.z * D + c;
    int4 a0 = *reinterpret_cast<const int4*>(ra);
    int4 a1 = *reinterpret_cast<const int4*>(ra + 8);
    int4 b0 = *reinterpret_cast<const int4*>(rb);
    int4 b1 = *reinterpret_cast<const int4*>(rb + 8);
    float wa = __int_as_float(e2.y), wb = __int_as_float(e2.w);
    bf8_fma(a0, wa, acc);
    bf8_fma(a1, wa, acc + 8);
    bf8_fma(b0, wb, acc);
    bf8_fma(b1, wb, acc + 8);
  }
  if (i < pe) {
    int2 e = epack[i];
    const ushort* rp = Xb + (size_t)e.x * D + c;
    int4 v0 = *reinterpret_cast<const int4*>(rp);
    int4 v1 = *reinterpret_cast<const int4*>(rp + 8);
    float w = __int_as_float(e.y);
    bf8_fma(v0, w, acc);
    bf8_fma(v1, w, acc + 8);
  }
  ushort h[16];
#pragma unroll
  for (int j = 0; j < 16; j++) h[j] = f2h(acc[j]);
  size_t o = (size_t)row * D + c;
  *reinterpret_cast<ushort4*>(AH + o)      = make_ushort4(h[0], h[1], h[2], h[3]);
  *reinterpret_cast<ushort4*>(AH + o + 4)  = make_ushort4(h[4], h[5], h[6], h[7]);
  *reinterpret_cast<ushort4*>(AH + o + 8)  = make_ushort4(h[8], h[9], h[10], h[11]);
  *reinterpret_cast<ushort4*>(AH + o + 12) = make_ushort4(h[12], h[13], h[14], h[15]);
}

// ================= fp16 MFMA GEMM: Y = relu(A @ W + b), bf16 out ==========

template<int KT, int NT>
__global__ __launch_bounds__(256)
void k_gemm_mfma(const ushort* __restrict__ Ah, const ushort* __restrict__ Bh,
                 const float* __restrict__ bias, ushort* __restrict__ Y,
                 int N, int D) {
  constexpr int PK = 72;
  __shared__ __align__(16) ushort sAh[128 * PK];
  __shared__ __align__(16) ushort sBh[NT * PK];
  const int t = threadIdx.x;
  const int wave = t >> 6, lane = t & 63;
  const int quad = lane >> 4, l16 = lane & 15;
  const int m0 = blockIdx.y * 128;
  const int n0 = blockIdx.x * NT;

  f32x4 acc[2][NT / 16];
#pragma unroll
  for (int mi = 0; mi < 2; mi++)
#pragma unroll
    for (int ni = 0; ni < NT / 16; ni++) acc[mi][ni] = (f32x4){0.f, 0.f, 0.f, 0.f};

  for (int k0 = 0; k0 < KT; k0 += 64) {
    if (k0) __syncthreads();
#pragma unroll
    for (int it = 0; it < 4; it++) {
      int c = t + 256 * it;
      int row = c >> 3, kc = (c & 7) << 3;
      int gr = m0 + row; if (gr >= N) gr = N - 1;
      *reinterpret_cast<int4*>(&sAh[row * PK + kc]) =
          *reinterpret_cast<const int4*>(Ah + (size_t)gr * KT + k0 + kc);
    }
#pragma unroll
    for (int it = 0; it < NT / 32; it++) {
      int c = t + 256 * it;
      int row = c >> 3, kc = (c & 7) << 3;
      *reinterpret_cast<int4*>(&sBh[row * PK + kc]) =
          *reinterpret_cast<const int4*>(Bh + (size_t)(n0 + row) * KT + k0 + kc);
    }
    __syncthreads();
#pragma unroll
    for (int ks = 0; ks < 2; ks++) {
      const int kk = ks * 32 + quad * 8;
      f16x8 aH[2];
#pragma unroll
      for (int mi = 0; mi < 2; mi++) {
        int r = wave * 32 + mi * 16 + l16;
        aH[mi] = *reinterpret_cast<const f16x8*>(&sAh[r * PK + kk]);
      }
#pragma unroll
      for (int ni = 0; ni < NT / 16; ni++) {
        int r = ni * 16 + l16;
        f16x8 bH = *reinterpret_cast<const f16x8*>(&sBh[r * PK + kk]);
#pragma unroll
        for (int mi = 0; mi < 2; mi++)
          acc[mi][ni] = __builtin_amdgcn_mfma_f32_16x16x32_f16(aH[mi], bH, acc[mi][ni], 0, 0, 0);
      }
    }
  }
#pragma unroll
  for (int mi = 0; mi < 2; mi++) {
    int rb = m0 + wave * 32 + mi * 16 + quad * 4;
#pragma unroll
    for (int ni = 0; ni < NT / 16; ni++) {
      int col = n0 + ni * 16 + l16;
      float bv = bias[col];
#pragma unroll
      for (int r = 0; r < 4; r++) {
        int row = rb + r;
        if (row < N)
          Y[(size_t)row * D + col] = f2bf(fmaxf(acc[mi][ni][r] + bv, 0.f));
      }
    }
  }
}

// ================= pooling (sorted protein_batch; count fused c==0) =======

__global__ void k_pool(const ushort* __restrict__ X3b, const float* __restrict__ feat,
                       const int* __restrict__ pb, double* __restrict__ psum,
                       float* __restrict__ gcnt, int N, int D3, int F) {
  const int c = threadIdx.x;
  const int C = D3 + F;
  int i0 = blockIdx.x * 64;
  if (i0 >= N) return;
  int iend = i0 + 64; if (iend > N) iend = N;
  double acc = 0.0;
  float cacc = 0.f;
  int cur = pb[i0];
  for (int i = i0; i < iend; i++) {
    int b = pb[i];
    if (b != cur) {
      atomicAdd(&psum[(size_t)cur * C + c], acc);
      if (c == 0) atomicAdd(&gcnt[cur], cacc);
      acc = 0.0; cacc = 0.f; cur = b;
    }
    float v;
    if (c < D3) v = bf2f(X3b[(size_t)i * D3 + c]);
    else        v = feat[(size_t)i * F + (c - D3)];
    acc += (double)v;
    cacc += 1.f;
  }
  atomicAdd(&psum[(size_t)cur * C + c], acc);
  if (c == 0) atomicAdd(&gcnt[cur], cacc);
}

// ================= FC head (gc normalization fused into fc1) ==============

__global__ __launch_bounds__(256)
void k_fc1(const double* __restrict__ psum, const float* __restrict__ cnt,
           const float* __restrict__ Wf1, const float* __restrict__ bf1,
           float* __restrict__ hidden, int C, int Hh) {
  const int b = blockIdx.y;
  __shared__ float gcs[384];
  float invc = 1.f / fmaxf(cnt[b], 1.f);
  for (int c = threadIdx.x; c < C; c += 256)
    gcs[c] = (float)psum[(size_t)b * C + c] * invc;
  __syncthreads();
  const int j = blockIdx.x * 256 + threadIdx.x;
  if (j >= Hh) return;
  const float* w = Wf1 + j;
  float a0 = 0.f, a1 = 0.f, a2 = 0.f, a3 = 0.f;
  int c = 0;
  for (; c + 4 <= C; c += 4) {
    a0 = fmaf(gcs[c + 0], w[(size_t)(c + 0) * Hh], a0);
    a1 = fmaf(gcs[c + 1], w[(size_t)(c + 1) * Hh], a1);
    a2 = fmaf(gcs[c + 2], w[(size_t)(c + 2) * Hh], a2);
    a3 = fmaf(gcs[c + 3], w[(size_t)(c + 3) * Hh], a3);
  }
  for (; c < C; c++) a0 = fmaf(gcs[c], w[(size_t)c * Hh], a0);
  float r = ((a0 + a1) + (a2 + a3)) + bf1[j];
  hidden[(size_t)b * Hh + j] = fmaxf(r, 0.f);
}

__global__ void k_fc2(const float* __restrict__ hidden, const float* __restrict__ Wf2,
                      const float* __restrict__ bf2, float* __restrict__ out, int Hh) {
  int b = blockIdx.x;
  int lane = threadIdx.x;  // 64
  double s = 0.0;
  for (int j = lane; j < Hh; j += 64) s += (double)hidden[(size_t)b * Hh + j] * (double)Wf2[j];
#pragma unroll
  for (int off = 32; off > 0; off >>= 1) s += __shfl_down(s, off);
  if (lane == 0) out[b] = (float)s + bf2[0];
}

// ================= launch =================

extern "C" void kernel_launch(void* const* d_in, const int* in_sizes, int n_in,
                              void* d_out, int out_size, void* d_ws, size_t ws_size,
                              hipStream_t stream) {
  const float* feature = (const float*)d_in[0];
  const int*   eidx    = (const int*)  d_in[1];
  const float* weight  = (const float*)d_in[2];
  const int*   pb      = (const int*)  d_in[3];
  const float* W1  = (const float*)d_in[4];
  const float* b1  = (const float*)d_in[5];
  const float* W2  = (const float*)d_in[6];
  const float* b2  = (const float*)d_in[7];
  const float* W3  = (const float*)d_in[8];
  const float* b3  = (const float*)d_in[9];
  const float* Wf1 = (const float*)d_in[10];
  const float* bf1 = (const float*)d_in[11];
  const float* Wf2 = (const float*)d_in[12];
  const float* bf2 = (const float*)d_in[13];

  const int F  = in_sizes[5];          // 64
  const int D2 = in_sizes[7];          // 128
  const int D3 = in_sizes[9];          // 256
  const int Hh = in_sizes[11];         // 1024
  const int N  = in_sizes[0] / F;      // 100000
  const int E  = in_sizes[1] / 2;      // 1200000
  const int B  = out_size;             // 256
  const int C  = D3 + F;               // 320

  const int* srcp = eidx;
  const int* dstp = eidx + E;

  const int NB   = (N + 255) / 256;        // buckets (<=512)
  const int NBLK = (E + EPB - 1) / EPB;    // edge blocks
  const int T    = NB * NBLK;              // scan length
  const int nscanb = (T + 1023) / 1024;
  const int nscan  = (N + 1023) / 1024;

  auto al = [](size_t x) { return (x + 255) & ~(size_t)255; };
  size_t off = 0;
  auto alloc = [&](size_t bytes) { size_t o = off; off += al(bytes); return o; };
  size_t o_H     = alloc((size_t)T * 4);
  size_t o_S     = alloc((size_t)T * 4);
  size_t o_bsb   = alloc((size_t)nscanb * 4);
  size_t o_sdst  = alloc((size_t)E * 4);
  size_t o_ssw   = alloc((size_t)E * 8);
  size_t o_cntN  = alloc((size_t)N * 4);
  size_t o_wsumN = alloc((size_t)N * 4);
  size_t o_dinv  = alloc((size_t)N * 4);
  size_t o_sn    = alloc((size_t)N * 4);
  size_t o_rs    = alloc((size_t)(N + 1) * 4);
  size_t o_bsum  = alloc((size_t)nscan * 4);
  size_t o_epack = alloc((size_t)E * 8);
  size_t o_featb = alloc((size_t)N * F  * 2);
  size_t o_x1b   = alloc((size_t)N * F  * 2);
  size_t o_x2b   = alloc((size_t)N * D2 * 2);
  size_t o_x3b   = alloc((size_t)N * D3 * 2);
  size_t o_aggh  = alloc((size_t)N * D2 * 2);   // fp16 (max K = 128)
  size_t o_w1h   = alloc((size_t)F  * F  * 2);
  size_t o_w2h   = alloc((size_t)F  * D2 * 2);
  size_t o_w3h   = alloc((size_t)D2 * D3 * 2);
  size_t o_psum  = alloc((size_t)B * C * 8);
  size_t o_gcnt  = alloc((size_t)B * 4);
  size_t o_hid   = alloc((size_t)B * Hh * 4);
  if (off > ws_size) {
    fprintf(stderr, "kernel_launch: workspace too small: need %zu, have %zu\n", off, ws_size);
    return;
  }

  char* ws = (char*)d_ws;
  int*    H     = (int*)  (ws + o_H);
  int*    S     = (int*)  (ws + o_S);
  int*    bsb   = (int*)  (ws + o_bsb);
  int*    sdst  = (int*)  (ws + o_sdst);
  int2*   ssw   = (int2*) (ws + o_ssw);
  int*    cntN  = (int*)  (ws + o_cntN);
  float*  wsumN = (float*)(ws + o_wsumN);
  float*  dinv  = (float*)(ws + o_dinv);
  float*  sn    = (float*)(ws + o_sn);
  int*    rs    = (int*)  (ws + o_rs);
  int*    bsum  = (int*)  (ws + o_bsum);
  int2*   epack = (int2*) (ws + o_epack);
  ushort* featb = (ushort*)(ws + o_featb);
  ushort* x1b   = (ushort*)(ws + o_x1b);
  ushort* x2b   = (ushort*)(ws + o_x2b);
  ushort* x3b   = (ushort*)(ws + o_x3b);
  ushort* aggh  = (ushort*)(ws + o_aggh);
  ushort* w1h   = (ushort*)(ws + o_w1h);
  ushort* w2h   = (ushort*)(ws + o_w2h);
  ushort* w3h   = (ushort*)(ws + o_w3h);
  double* psum  = (double*)(ws + o_psum);
  float*  gcnt  = (float*)(ws + o_gcnt);
  float*  hid   = (float*)(ws + o_hid);
  float*  out   = (float*)d_out;

  // ---- fused prep ----
  const int BC = B * C, NF = N * F;
  const int nB = (BC + 255) / 256;
  const int nC = (NF / 4 + 255) / 256;
  const int nD = (F * F + F * D2 + D2 * D3 + 255) / 256;
  k_prep<<<nB + nC + nD, 256, 0, stream>>>(
      psum, gcnt, feature, featb, W1, w1h, W2, w2h, W3, w3h,
      BC, B, NF, F, D2, D3, nB, nC);

  // ---- sort-based CSR build (zero global atomics) ----
  k_bhist   <<<NBLK, 256, 0, stream>>>(dstp, H, NB, E);
  k_bscan1  <<<nscanb, 256, 0, stream>>>(H, S, bsb, NB, NBLK, T);
  k_bscan23 <<<(T + 255) / 256, 256, 0, stream>>>(S, bsb, T);
  k_bscatter<<<NBLK, 256, 0, stream>>>(srcp, dstp, weight, S, sdst, ssw, NB, NBLK, E);
  k_bprocA  <<<NB, 256, 0, stream>>>(sdst, ssw, S, cntN, wsumN, NB, NBLK, N, E);
  k_scan1   <<<nscan, 256, 0, stream>>>(cntN, wsumN, rs, bsum, dinv, sn, N);
  k_scan23  <<<(N + 255) / 256, 256, 0, stream>>>(rs, bsum, N, E);
  k_bprocB  <<<NB, 256, 0, stream>>>(sdst, ssw, S, rs, dinv, epack, NB, NBLK, N, E);

  const int gy = (N + 127) / 128;

  // ---- layer 1: agg(featb)[N,64] @ W1[64,64] -> x1b (bf16) ----
  {
    int tot = N * (F / 16);
    k_aggregate_b<2><<<(tot + 255) / 256, 256, 0, stream>>>(featb, rs, epack, sn, aggh, N);
    dim3 g(1, gy);
    k_gemm_mfma<64, 64><<<g, 256, 0, stream>>>(aggh, w1h, b1, x1b, N, F);
  }
  // ---- layer 2: agg(x1b)[N,64] @ W2[64,128] -> x2b (bf16) ----
  {
    int tot = N * (F / 16);
    k_aggregate_b<2><<<(tot + 255) / 256, 256, 0, stream>>>(x1b, rs, epack, sn, aggh, N);
    dim3 g(1, gy);
    k_gemm_mfma<64, 128><<<g, 256, 0, stream>>>(aggh, w2h, b2, x2b, N, D2);
  }
  // ---- layer 3: agg(x2b)[N,128] @ W3[128,256] -> x3b (bf16) ----
  {
    int tot = N * (D2 / 16);
    k_aggregate_b<3><<<(tot + 255) / 256, 256, 0, stream>>>(x2b, rs, epack, sn, aggh, N);
    dim3 g(2, gy);
    k_gemm_mfma<128, 128><<<g, 256, 0, stream>>>(aggh, w3h, b3, x3b, N, D3);
  }

  // ---- pooling + head ----
  k_pool <<<(N + 63) / 64, C, 0, stream>>>(x3b, feature, pb, psum, gcnt, N, D3, F);
  {
    dim3 g((Hh + 255) / 256, B);
    k_fc1<<<g, 256, 0, stream>>>(psum, gcnt, Wf1, bf1, hid, C, Hh);
  }
  k_fc2  <<<B, 64, 0, stream>>>(hid, Wf2, bf2, out, Hh);
}